// Round 1
// baseline (1429.068 us; speedup 1.0000x reference)
//
#include <hip/hip_runtime.h>
#include <cstdint>
#include <cstddef>

#define HD 4096
#define EE 8
#define LL 8
#define RR 4
#define VV 32000
#define NTOK 2048

typedef __attribute__((ext_vector_type(8))) short bf16x8;
typedef __attribute__((ext_vector_type(4))) float f32x4;
typedef unsigned short ushort_t;

static __device__ __forceinline__ unsigned short f2bf(float f) {
    unsigned int u = __builtin_bit_cast(unsigned int, f);
    unsigned int r = (u + 0x7FFFu + ((u >> 16) & 1u)) >> 16;
    return (unsigned short)r;
}

// ---------------------------------------------------------------------------
// Kernel 1: router (double softmax) + 8 fused LoRA layers.
// 512 blocks x 256 threads; 4 tokens per block; h in LDS (fp32) end-to-end.
// ---------------------------------------------------------------------------
__global__ __launch_bounds__(256) void fused_layers(
    const float* __restrict__ h_in,       // [2048][4096]
    const float* __restrict__ router_w,   // [8][4096]
    const float* __restrict__ router_b,   // [8]
    const float* __restrict__ expert_B,   // [E][L][R][H]
    const float* __restrict__ expert_A,   // [E][L][H][R]
    const float* __restrict__ deep_B,     // [L][R][H]
    const float* __restrict__ deep_A,     // [L][H][R]
    float* __restrict__ router_logits,    // [2048][8]
    unsigned short* __restrict__ h_out)   // [2048][4096] bf16
{
    __shared__ float h_lds[4][HD];        // 64 KB
    __shared__ float zw_lds[4][32];
    __shared__ float probs_lds[4][EE];
    __shared__ float psum_lds[4];
    __shared__ float red[4][4][4];        // [wave][token][r]
    __shared__ float low_lds[4][4];

    const int tid  = threadIdx.x;
    const int lane = tid & 63;
    const int wv   = tid >> 6;
    const int t0   = blockIdx.x * 4;

    // ---- load h tile (4 tokens x 4096 fp32), coalesced float4
    for (int t = 0; t < 4; ++t) {
        const float4* src = (const float4*)(h_in + (size_t)(t0 + t) * HD);
        float4* dst = (float4*)h_lds[t];
        #pragma unroll
        for (int q = 0; q < 4; ++q) dst[tid + q * 256] = src[tid + q * 256];
    }
    __syncthreads();

    // ---- router: wave wv handles token t0+wv
    {
        float racc[EE];
        #pragma unroll
        for (int e = 0; e < EE; ++e) racc[e] = 0.f;
        for (int k = 0; k < HD / 64; ++k) {
            int pos = lane + k * 64;
            float hv = h_lds[wv][pos];
            #pragma unroll
            for (int e = 0; e < EE; ++e) racc[e] += hv * router_w[e * HD + pos];
        }
        #pragma unroll
        for (int e = 0; e < EE; ++e)
            for (int m = 1; m < 64; m <<= 1) racc[e] += __shfl_xor(racc[e], m);
        if (lane == 0) {
            float lg[EE], mx = -1e30f;
            #pragma unroll
            for (int e = 0; e < EE; ++e) { lg[e] = racc[e] + router_b[e]; mx = fmaxf(mx, lg[e]); }
            float s = 0.f;
            #pragma unroll
            for (int e = 0; e < EE; ++e) { lg[e] = expf(lg[e] - mx); s += lg[e]; }
            float inv = 1.f / s;
            float p1[EE], mx2 = -1e30f;
            #pragma unroll
            for (int e = 0; e < EE; ++e) { p1[e] = lg[e] * inv; mx2 = fmaxf(mx2, p1[e]); }
            float s2 = 0.f, q2[EE];
            #pragma unroll
            for (int e = 0; e < EE; ++e) { q2[e] = expf(p1[e] - mx2); s2 += q2[e]; }
            float inv2 = 1.f / s2, ps = 0.f;
            #pragma unroll
            for (int e = 0; e < EE; ++e) {
                float p2 = q2[e] * inv2;
                probs_lds[wv][e] = p2;
                ps += p2;
                router_logits[(size_t)(t0 + wv) * EE + e] = p1[e];  // first softmax is the output
            }
            psum_lds[wv] = ps;
        }
    }
    __syncthreads();

    // ---- 8 layers
    for (int li = 0; li < LL; ++li) {
        // ---- Z phase: wave wv owns (e,r) pairs [wv*8, wv*8+8), all 4 tokens
        {
            float zacc[8][4] = {};
            const float* bp[8];
            #pragma unroll
            for (int j = 0; j < 8; ++j) {
                int er = wv * 8 + j;
                int e = er >> 2, r = er & 3;
                bp[j] = expert_B + (size_t)(e * LL + li) * (RR * HD) + (size_t)r * HD;
            }
            for (int k = 0; k < 64; ++k) {
                int pos = lane + k * 64;
                float hv0 = h_lds[0][pos], hv1 = h_lds[1][pos];
                float hv2 = h_lds[2][pos], hv3 = h_lds[3][pos];
                #pragma unroll
                for (int j = 0; j < 8; ++j) {
                    float wt = bp[j][pos];
                    zacc[j][0] += wt * hv0; zacc[j][1] += wt * hv1;
                    zacc[j][2] += wt * hv2; zacc[j][3] += wt * hv3;
                }
            }
            #pragma unroll
            for (int j = 0; j < 8; ++j)
                #pragma unroll
                for (int t = 0; t < 4; ++t) {
                    float v = zacc[j][t];
                    for (int m = 1; m < 64; m <<= 1) v += __shfl_xor(v, m);
                    zacc[j][t] = v;
                }
            if (lane == 0) {
                #pragma unroll
                for (int j = 0; j < 8; ++j) {
                    int er = wv * 8 + j;
                    #pragma unroll
                    for (int t = 0; t < 4; ++t)
                        zw_lds[t][er] = zacc[j][t] * probs_lds[t][er >> 2];
                }
            }
        }
        __syncthreads();

        // ---- delta phase: wave wv owns H-chunk [wv*1024, wv*1024+1024)
        float dacc[4][16] = {};   // [token][it], fully static indexing
        const int pbase = wv * 1024 + lane;
        for (int e = 0; e < EE; ++e) {
            float zwt[4][4];
            #pragma unroll
            for (int t = 0; t < 4; ++t)
                #pragma unroll
                for (int r = 0; r < RR; ++r) zwt[t][r] = zw_lds[t][e * 4 + r];
            const float4* ap = (const float4*)expert_A + (size_t)(e * LL + li) * HD;
            #pragma unroll
            for (int it = 0; it < 16; ++it) {
                float4 a4 = ap[pbase + it * 64];
                #pragma unroll
                for (int t = 0; t < 4; ++t)
                    dacc[t][it] += zwt[t][0] * a4.x + zwt[t][1] * a4.y +
                                   zwt[t][2] * a4.z + zwt[t][3] * a4.w;
            }
        }

        // ---- combined = h*psum + delta; write back; deep-B low partials
        float lowacc[4][4] = {};
        float psv[4];
        #pragma unroll
        for (int t = 0; t < 4; ++t) psv[t] = psum_lds[t];
        const float* dbp = deep_B + (size_t)li * (RR * HD);
        #pragma unroll
        for (int it = 0; it < 16; ++it) {
            int pos = pbase + it * 64;
            float db0 = dbp[pos], db1 = dbp[HD + pos], db2 = dbp[2 * HD + pos], db3 = dbp[3 * HD + pos];
            #pragma unroll
            for (int t = 0; t < 4; ++t) {
                float c = h_lds[t][pos] * psv[t] + dacc[t][it];
                h_lds[t][pos] = c;
                lowacc[t][0] += c * db0; lowacc[t][1] += c * db1;
                lowacc[t][2] += c * db2; lowacc[t][3] += c * db3;
            }
        }
        #pragma unroll
        for (int t = 0; t < 4; ++t)
            #pragma unroll
            for (int r = 0; r < RR; ++r) {
                float v = lowacc[t][r];
                for (int m = 1; m < 64; m <<= 1) v += __shfl_xor(v, m);
                lowacc[t][r] = v;
            }
        if (lane == 0) {
            #pragma unroll
            for (int t = 0; t < 4; ++t)
                #pragma unroll
                for (int r = 0; r < RR; ++r) red[wv][t][r] = lowacc[t][r];
        }
        __syncthreads();
        if (tid < 16) {
            int t = tid >> 2, r = tid & 3;
            low_lds[t][r] = red[0][t][r] + red[1][t][r] + red[2][t][r] + red[3][t][r];
        }
        __syncthreads();

        // ---- up phase: h += low @ deep_A^T (own H-chunk)
        {
            float lw[4][4];
            #pragma unroll
            for (int t = 0; t < 4; ++t)
                #pragma unroll
                for (int r = 0; r < RR; ++r) lw[t][r] = low_lds[t][r];
            const float4* dap = (const float4*)deep_A + (size_t)li * HD;
            #pragma unroll
            for (int it = 0; it < 16; ++it) {
                int pos = pbase + it * 64;
                float4 a4 = dap[pos];
                #pragma unroll
                for (int t = 0; t < 4; ++t)
                    h_lds[t][pos] += lw[t][0] * a4.x + lw[t][1] * a4.y +
                                     lw[t][2] * a4.z + lw[t][3] * a4.w;
            }
        }
        __syncthreads();
    }

    // ---- epilogue: h -> bf16 into workspace
    for (int t = 0; t < 4; ++t) {
        ushort4* dst = (ushort4*)(h_out + (size_t)(t0 + t) * HD);
        const float4* src = (const float4*)h_lds[t];
        #pragma unroll
        for (int q = 0; q < 4; ++q) {
            int c = tid + q * 256;
            float4 v = src[c];
            ushort4 o;
            o.x = f2bf(v.x); o.y = f2bf(v.y); o.z = f2bf(v.z); o.w = f2bf(v.w);
            dst[c] = o;
        }
    }
}

// ---------------------------------------------------------------------------
// Kernel 2: lm_head_w fp32 -> bf16
// ---------------------------------------------------------------------------
__global__ __launch_bounds__(256) void cvt_kernel(const float4* __restrict__ in,
                                                  ushort4* __restrict__ out, int n4)
{
    int i = blockIdx.x * 256 + threadIdx.x;
    int stride = gridDim.x * 256;
    for (; i < n4; i += stride) {
        float4 v = in[i];
        ushort4 o;
        o.x = f2bf(v.x); o.y = f2bf(v.y); o.z = f2bf(v.z); o.w = f2bf(v.w);
        out[i] = o;
    }
}

// ---------------------------------------------------------------------------
// Kernel 3: lm_head GEMM  C[2048][32000] = A[2048][4096] * B[32000][4096]^T
// bf16 MFMA 16x16x32, 128x128 tile, BK=64, global_load_lds width-16 staging.
// ---------------------------------------------------------------------------
__global__ __launch_bounds__(256) void lm_gemm(
    const unsigned short* __restrict__ A,   // bf16 [2048][4096]
    const unsigned short* __restrict__ Bw,  // bf16 [32000][4096]
    float* __restrict__ C)                  // [2048][32000]
{
    constexpr int K = HD;
    __shared__ unsigned short As[128 * 64];
    __shared__ unsigned short Bs[128 * 64];

    const int bid = blockIdx.x;
    const int bm = bid & 15;    // m fastest: consecutive blocks share the B tile
    const int bn = bid >> 4;
    const int tid = threadIdx.x;
    const int lane = tid & 63;
    const int wv = tid >> 6;
    const int wm = (wv & 1) << 6;
    const int wn = (wv >> 1) << 6;

    f32x4 acc[4][4] = {};

    const int srow = tid >> 3;          // 0..31
    const int scol = (tid & 7) << 4;    // byte col within 128B row

    const char* Agp = (const char*)(A + (size_t)(bm * 128) * K);
    const char* Bgp = (const char*)(Bw + (size_t)(bn * 128) * K);
    char* AsB = (char*)As;
    char* BsB = (char*)Bs;

    for (int kt = 0; kt < K / 64; ++kt) {
        const size_t kb = (size_t)kt * 128;   // byte offset along K
        #pragma unroll
        for (int q = 0; q < 4; ++q) {
            const char* ga = Agp + (size_t)(q * 32 + srow) * (K * 2) + kb + scol;
            const char* gb = Bgp + (size_t)(q * 32 + srow) * (K * 2) + kb + scol;
            __builtin_amdgcn_global_load_lds(
                (const __attribute__((address_space(1))) unsigned int*)ga,
                (__attribute__((address_space(3))) unsigned int*)(AsB + q * 4096 + wv * 1024),
                16, 0, 0);
            __builtin_amdgcn_global_load_lds(
                (const __attribute__((address_space(1))) unsigned int*)gb,
                (__attribute__((address_space(3))) unsigned int*)(BsB + q * 4096 + wv * 1024),
                16, 0, 0);
        }
        __syncthreads();

        #pragma unroll
        for (int ks = 0; ks < 2; ++ks) {
            const int colb = ks * 64 + ((lane >> 4) << 4);
            bf16x8 af[4], bfm[4];
            #pragma unroll
            for (int m = 0; m < 4; ++m)
                af[m] = *(const bf16x8*)(AsB + (wm + m * 16 + (lane & 15)) * 128 + colb);
            #pragma unroll
            for (int n = 0; n < 4; ++n)
                bfm[n] = *(const bf16x8*)(BsB + (wn + n * 16 + (lane & 15)) * 128 + colb);
            #pragma unroll
            for (int m = 0; m < 4; ++m)
                #pragma unroll
                for (int n = 0; n < 4; ++n)
                    acc[m][n] = __builtin_amdgcn_mfma_f32_16x16x32_bf16(
                        af[m], bfm[n], acc[m][n], 0, 0, 0);
        }
        __syncthreads();
    }

    // epilogue: D row = (lane>>4)*4+j (m dim), col = lane&15 (n dim)
    const int crow0 = bm * 128 + wm + ((lane >> 4) << 2);
    const int ccol0 = bn * 128 + wn + (lane & 15);
    #pragma unroll
    for (int m = 0; m < 4; ++m)
        #pragma unroll
        for (int n = 0; n < 4; ++n) {
            int row = crow0 + m * 16;
            int col = ccol0 + n * 16;
            #pragma unroll
            for (int j = 0; j < 4; ++j)
                C[(size_t)(row + j) * VV + col] = acc[m][n][j];
        }
}

// ---------------------------------------------------------------------------
extern "C" void kernel_launch(void* const* d_in, const int* in_sizes, int n_in,
                              void* d_out, int out_size, void* d_ws, size_t ws_size,
                              hipStream_t stream) {
    const float* h_in      = (const float*)d_in[0];
    const float* router_w  = (const float*)d_in[1];
    const float* router_b  = (const float*)d_in[2];
    const float* expert_B  = (const float*)d_in[3];
    const float* expert_A  = (const float*)d_in[4];
    const float* deep_B    = (const float*)d_in[5];
    const float* deep_A    = (const float*)d_in[6];
    const float* lm_head_w = (const float*)d_in[7];

    float* out = (float*)d_out;
    float* router_logits_out = out + (size_t)NTOK * VV;

    unsigned short* h_bf = (unsigned short*)d_ws;                                  // 16 MB
    unsigned short* w_bf = (unsigned short*)((char*)d_ws + (size_t)NTOK * HD * 2); // 262 MB

    fused_layers<<<dim3(NTOK / 4), dim3(256), 0, stream>>>(
        h_in, router_w, router_b, expert_B, expert_A, deep_B, deep_A,
        router_logits_out, h_bf);

    cvt_kernel<<<dim3(4096), dim3(256), 0, stream>>>(
        (const float4*)lm_head_w, (ushort4*)w_bf, VV * HD / 4);

    lm_gemm<<<dim3((NTOK / 128) * (VV / 128)), dim3(256), 0, stream>>>(
        h_bf, w_bf, out);
}

// Round 2
// 1068.329 us; speedup vs baseline: 1.3377x; 1.3377x over previous
//
#include <hip/hip_runtime.h>
#include <cstdint>
#include <cstddef>

#define HD 4096
#define EE 8
#define LL 8
#define RR 4
#define VV 32000
#define NTOK 2048
#define NKT (HD / 64)   // 64 K-tiles of BK=64

typedef __attribute__((ext_vector_type(8))) short bf16x8;
typedef __attribute__((ext_vector_type(4))) float f32x4;

static __device__ __forceinline__ unsigned short f2bf(float f) {
    unsigned int u = __builtin_bit_cast(unsigned int, f);
    unsigned int r = (u + 0x7FFFu + ((u >> 16) & 1u)) >> 16;
    return (unsigned short)r;
}

// ---------------------------------------------------------------------------
// Kernel 1: router (double softmax) + 8 fused LoRA layers. (unchanged R1)
// ---------------------------------------------------------------------------
__global__ __launch_bounds__(256) void fused_layers(
    const float* __restrict__ h_in,
    const float* __restrict__ router_w,
    const float* __restrict__ router_b,
    const float* __restrict__ expert_B,
    const float* __restrict__ expert_A,
    const float* __restrict__ deep_B,
    const float* __restrict__ deep_A,
    float* __restrict__ router_logits,
    unsigned short* __restrict__ h_out)
{
    __shared__ float h_lds[4][HD];
    __shared__ float zw_lds[4][32];
    __shared__ float probs_lds[4][EE];
    __shared__ float psum_lds[4];
    __shared__ float red[4][4][4];
    __shared__ float low_lds[4][4];

    const int tid  = threadIdx.x;
    const int lane = tid & 63;
    const int wv   = tid >> 6;
    const int t0   = blockIdx.x * 4;

    for (int t = 0; t < 4; ++t) {
        const float4* src = (const float4*)(h_in + (size_t)(t0 + t) * HD);
        float4* dst = (float4*)h_lds[t];
        #pragma unroll
        for (int q = 0; q < 4; ++q) dst[tid + q * 256] = src[tid + q * 256];
    }
    __syncthreads();

    {
        float racc[EE];
        #pragma unroll
        for (int e = 0; e < EE; ++e) racc[e] = 0.f;
        for (int k = 0; k < HD / 64; ++k) {
            int pos = lane + k * 64;
            float hv = h_lds[wv][pos];
            #pragma unroll
            for (int e = 0; e < EE; ++e) racc[e] += hv * router_w[e * HD + pos];
        }
        #pragma unroll
        for (int e = 0; e < EE; ++e)
            for (int m = 1; m < 64; m <<= 1) racc[e] += __shfl_xor(racc[e], m);
        if (lane == 0) {
            float lg[EE], mx = -1e30f;
            #pragma unroll
            for (int e = 0; e < EE; ++e) { lg[e] = racc[e] + router_b[e]; mx = fmaxf(mx, lg[e]); }
            float s = 0.f;
            #pragma unroll
            for (int e = 0; e < EE; ++e) { lg[e] = expf(lg[e] - mx); s += lg[e]; }
            float inv = 1.f / s;
            float p1[EE], mx2 = -1e30f;
            #pragma unroll
            for (int e = 0; e < EE; ++e) { p1[e] = lg[e] * inv; mx2 = fmaxf(mx2, p1[e]); }
            float s2 = 0.f, q2[EE];
            #pragma unroll
            for (int e = 0; e < EE; ++e) { q2[e] = expf(p1[e] - mx2); s2 += q2[e]; }
            float inv2 = 1.f / s2, ps = 0.f;
            #pragma unroll
            for (int e = 0; e < EE; ++e) {
                float p2 = q2[e] * inv2;
                probs_lds[wv][e] = p2;
                ps += p2;
                router_logits[(size_t)(t0 + wv) * EE + e] = p1[e];
            }
            psum_lds[wv] = ps;
        }
    }
    __syncthreads();

    for (int li = 0; li < LL; ++li) {
        {
            float zacc[8][4] = {};
            const float* bp[8];
            #pragma unroll
            for (int j = 0; j < 8; ++j) {
                int er = wv * 8 + j;
                int e = er >> 2, r = er & 3;
                bp[j] = expert_B + (size_t)(e * LL + li) * (RR * HD) + (size_t)r * HD;
            }
            for (int k = 0; k < 64; ++k) {
                int pos = lane + k * 64;
                float hv0 = h_lds[0][pos], hv1 = h_lds[1][pos];
                float hv2 = h_lds[2][pos], hv3 = h_lds[3][pos];
                #pragma unroll
                for (int j = 0; j < 8; ++j) {
                    float wt = bp[j][pos];
                    zacc[j][0] += wt * hv0; zacc[j][1] += wt * hv1;
                    zacc[j][2] += wt * hv2; zacc[j][3] += wt * hv3;
                }
            }
            #pragma unroll
            for (int j = 0; j < 8; ++j)
                #pragma unroll
                for (int t = 0; t < 4; ++t) {
                    float v = zacc[j][t];
                    for (int m = 1; m < 64; m <<= 1) v += __shfl_xor(v, m);
                    zacc[j][t] = v;
                }
            if (lane == 0) {
                #pragma unroll
                for (int j = 0; j < 8; ++j) {
                    int er = wv * 8 + j;
                    #pragma unroll
                    for (int t = 0; t < 4; ++t)
                        zw_lds[t][er] = zacc[j][t] * probs_lds[t][er >> 2];
                }
            }
        }
        __syncthreads();

        float dacc[4][16] = {};
        const int pbase = wv * 1024 + lane;
        for (int e = 0; e < EE; ++e) {
            float zwt[4][4];
            #pragma unroll
            for (int t = 0; t < 4; ++t)
                #pragma unroll
                for (int r = 0; r < RR; ++r) zwt[t][r] = zw_lds[t][e * 4 + r];
            const float4* ap = (const float4*)expert_A + (size_t)(e * LL + li) * HD;
            #pragma unroll
            for (int it = 0; it < 16; ++it) {
                float4 a4 = ap[pbase + it * 64];
                #pragma unroll
                for (int t = 0; t < 4; ++t)
                    dacc[t][it] += zwt[t][0] * a4.x + zwt[t][1] * a4.y +
                                   zwt[t][2] * a4.z + zwt[t][3] * a4.w;
            }
        }

        float lowacc[4][4] = {};
        float psv[4];
        #pragma unroll
        for (int t = 0; t < 4; ++t) psv[t] = psum_lds[t];
        const float* dbp = deep_B + (size_t)li * (RR * HD);
        #pragma unroll
        for (int it = 0; it < 16; ++it) {
            int pos = pbase + it * 64;
            float db0 = dbp[pos], db1 = dbp[HD + pos], db2 = dbp[2 * HD + pos], db3 = dbp[3 * HD + pos];
            #pragma unroll
            for (int t = 0; t < 4; ++t) {
                float c = h_lds[t][pos] * psv[t] + dacc[t][it];
                h_lds[t][pos] = c;
                lowacc[t][0] += c * db0; lowacc[t][1] += c * db1;
                lowacc[t][2] += c * db2; lowacc[t][3] += c * db3;
            }
        }
        #pragma unroll
        for (int t = 0; t < 4; ++t)
            #pragma unroll
            for (int r = 0; r < RR; ++r) {
                float v = lowacc[t][r];
                for (int m = 1; m < 64; m <<= 1) v += __shfl_xor(v, m);
                lowacc[t][r] = v;
            }
        if (lane == 0) {
            #pragma unroll
            for (int t = 0; t < 4; ++t)
                #pragma unroll
                for (int r = 0; r < RR; ++r) red[wv][t][r] = lowacc[t][r];
        }
        __syncthreads();
        if (tid < 16) {
            int t = tid >> 2, r = tid & 3;
            low_lds[t][r] = red[0][t][r] + red[1][t][r] + red[2][t][r] + red[3][t][r];
        }
        __syncthreads();

        {
            float lw[4][4];
            #pragma unroll
            for (int t = 0; t < 4; ++t)
                #pragma unroll
                for (int r = 0; r < RR; ++r) lw[t][r] = low_lds[t][r];
            const float4* dap = (const float4*)deep_A + (size_t)li * HD;
            #pragma unroll
            for (int it = 0; it < 16; ++it) {
                int pos = pbase + it * 64;
                float4 a4 = dap[pos];
                #pragma unroll
                for (int t = 0; t < 4; ++t)
                    h_lds[t][pos] += lw[t][0] * a4.x + lw[t][1] * a4.y +
                                     lw[t][2] * a4.z + lw[t][3] * a4.w;
            }
        }
        __syncthreads();
    }

    for (int t = 0; t < 4; ++t) {
        ushort4* dst = (ushort4*)(h_out + (size_t)(t0 + t) * HD);
        const float4* src = (const float4*)h_lds[t];
        #pragma unroll
        for (int q = 0; q < 4; ++q) {
            int c = tid + q * 256;
            float4 v = src[c];
            ushort4 o;
            o.x = f2bf(v.x); o.y = f2bf(v.y); o.z = f2bf(v.z); o.w = f2bf(v.w);
            dst[c] = o;
        }
    }
}

// ---------------------------------------------------------------------------
// Kernel 2: lm_head_w fp32 -> bf16 (unchanged)
// ---------------------------------------------------------------------------
__global__ __launch_bounds__(256) void cvt_kernel(const float4* __restrict__ in,
                                                  ushort4* __restrict__ out, int n4)
{
    int i = blockIdx.x * 256 + threadIdx.x;
    int stride = gridDim.x * 256;
    for (; i < n4; i += stride) {
        float4 v = in[i];
        ushort4 o;
        o.x = f2bf(v.x); o.y = f2bf(v.y); o.z = f2bf(v.z); o.w = f2bf(v.w);
        out[i] = o;
    }
}

// ---------------------------------------------------------------------------
// Kernel 3: 256x256 8-phase bf16 GEMM (m201 structure: T1+T2+T3+T4+T5)
// C[2048][32000] = A[2048][4096] * B[32000][4096]^T
//
// LDS layout per matrix K-tile buffer (32 KB = 256 rows x 64 cols bf16):
//   subtiled [r>>4][cb>>6] 1024B blocks, each 16 rows x 32 cols row-major,
//   st_16x32 swizzle: byte ^= ((byte>>9)&1)<<5.
// global_load_lds writes LINEAR; the inverse swizzle is applied to the
// per-lane GLOBAL source address (rule 21); ds_read applies the same XOR.
//
// Schedule per iteration kt (tile kt in buf[kt&1]=cur, kt+1 in oth):
//   P0: ds_read A-mh0(8)+B-nh0(4) | stage A0(kt+1)->oth | bar | MFMA q00 | bar
//   P1: ds_read B-nh1(4)          | stage A1(kt+1)->oth | bar | MFMA q01 | bar
//   P2: ds_read A-mh1(8)          | stage B0(kt+2)->cur | bar | MFMA q11 | bar
//   P3: (no reads, B-nh0 held)    | stage B1(kt+2)->cur | vmcnt(4) | bar | MFMA q10 | bar
// Ledger at P3 vmcnt: older = tile kt+1's 8 loads (must land);
// newer = tile kt+2's B0,B1 = 4 loads (stay in flight). Tail: vmcnt(0)
// when kt+2 prefetch suppressed.  Write-safety: B slots of cur last read
// P1 (barrier2-ordered before P2 issue); A slots last read P2 (before
// next-iter P0 issue).
// ---------------------------------------------------------------------------
#define GLD(src, dst) __builtin_amdgcn_global_load_lds( \
    (const __attribute__((address_space(1))) unsigned int*)(src), \
    (__attribute__((address_space(3))) unsigned int*)(dst), 16, 0, 0)

#define STAGE(pp, matoff, bufv, hh, ktv) do { \
    char* db_ = smem + (bufv) * 65536 + (matoff) + (hh) * 16384 + wv * 1024; \
    GLD(pp[0] + (size_t)(hh) * (128ull * HD * 2) + (size_t)(ktv) * 128, db_); \
    GLD(pp[1] + (size_t)(hh) * (128ull * HD * 2) + (size_t)(ktv) * 128, db_ + 8192); \
} while (0)

#define LDSREAD(off) (*(const bf16x8*)(smem + (off)))

__global__ __launch_bounds__(512, 2) void lm_gemm256(
    const unsigned short* __restrict__ A,   // bf16 [2048][4096]
    const unsigned short* __restrict__ Bw,  // bf16 [32000][4096]
    float* __restrict__ C)                  // [2048][32000]
{
    __shared__ __attribute__((aligned(128))) char smem[131072];

    // bijective XCD swizzle (1000 % 8 == 0), bm fastest for B-panel L2 reuse
    const int bid = blockIdx.x;
    const int swz = (bid & 7) * 125 + (bid >> 3);
    const int bm = swz & 7;       // 0..7   (M/256)
    const int bn = swz >> 3;      // 0..124 (N/256)

    const int tid  = threadIdx.x;
    const int lane = tid & 63;
    const int wv   = tid >> 6;
    const int wr   = wv >> 2;     // 0..1
    const int wc   = wv & 3;      // 0..3

    // staging: per thread 2 chunks; linear dest off=(q*512+tid)*16,
    // global source = swizzle-decoded logical position
    const char* pA[2];
    const char* pB[2];
    #pragma unroll
    for (int q = 0; q < 2; ++q) {
        int off = (q * 512 + tid) * 16;
        int p = off ^ (((off >> 9) & 1) << 5);
        int st = p >> 10;
        int r  = (st >> 1) * 16 + ((p >> 6) & 15);
        int cb = (st & 1) * 64 + (p & 63);
        pA[q] = (const char*)(A  + (size_t)(bm * 256 + r) * HD) + cb;
        pB[q] = (const char*)(Bw + (size_t)(bn * 256 + r) * HD) + cb;
    }

    // ds_read offset components (frag: row=lane&15, kbytes=(lane>>4)*16)
    const int xlane = ((lane >> 3) & 1) << 5;                    // swizzle XOR
    const int abase = ((wr * 8) << 11) + ((lane & 15) << 6) + ((lane >> 4) << 4);
    const int bbase = 32768 + ((wc * 4) << 11) + ((lane & 15) << 6) + ((lane >> 4) << 4);

    f32x4 acc[8][4] = {};
    bf16x8 aF[4][2], bF0[2][2], bF1[2][2];

    // prologue: tile0 {B0,B1,A0,A1}->buf0, tile1 {B0,B1}->buf1
    STAGE(pB, 32768, 0, 0, 0);
    STAGE(pB, 32768, 0, 1, 0);
    STAGE(pA, 0,     0, 0, 0);
    STAGE(pA, 0,     0, 1, 0);
    STAGE(pB, 32768, 1, 0, 1);
    STAGE(pB, 32768, 1, 1, 1);
    asm volatile("s_waitcnt vmcnt(4)" ::: "memory");   // tile0 landed; tile1 B in flight
    __builtin_amdgcn_s_barrier();
    __builtin_amdgcn_sched_barrier(0);

    #pragma unroll 2
    for (int kt = 0; kt < NKT; ++kt) {
        const int cur = kt & 1;
        const int oth = cur ^ 1;
        const int cb0 = cur << 16;

        // ---------------- PHASE 0 : quadrant (mh0, nh0)
        #pragma unroll
        for (int i = 0; i < 4; ++i)
            #pragma unroll
            for (int ks = 0; ks < 2; ++ks)
                aF[i][ks] = LDSREAD(cb0 + ((abase + (i << 11) + (ks << 10)) ^ xlane));
        #pragma unroll
        for (int n = 0; n < 2; ++n)
            #pragma unroll
            for (int ks = 0; ks < 2; ++ks)
                bF0[n][ks] = LDSREAD(cb0 + ((bbase + (n << 11) + (ks << 10)) ^ xlane));
        if (kt + 1 < NKT) STAGE(pA, 0, oth, 0, kt + 1);
        __builtin_amdgcn_s_barrier();
        __builtin_amdgcn_sched_barrier(0);
        __builtin_amdgcn_s_setprio(1);
        #pragma unroll
        for (int ks = 0; ks < 2; ++ks)
            #pragma unroll
            for (int i = 0; i < 4; ++i)
                #pragma unroll
                for (int n = 0; n < 2; ++n)
                    acc[i][n] = __builtin_amdgcn_mfma_f32_16x16x32_bf16(
                        aF[i][ks], bF0[n][ks], acc[i][n], 0, 0, 0);
        __builtin_amdgcn_s_setprio(0);
        __builtin_amdgcn_s_barrier();
        __builtin_amdgcn_sched_barrier(0);

        // ---------------- PHASE 1 : (mh0, nh1)
        #pragma unroll
        for (int n = 0; n < 2; ++n)
            #pragma unroll
            for (int ks = 0; ks < 2; ++ks)
                bF1[n][ks] = LDSREAD(cb0 + ((bbase + ((n + 2) << 11) + (ks << 10)) ^ xlane));
        if (kt + 1 < NKT) STAGE(pA, 0, oth, 1, kt + 1);
        __builtin_amdgcn_s_barrier();
        __builtin_amdgcn_sched_barrier(0);
        __builtin_amdgcn_s_setprio(1);
        #pragma unroll
        for (int ks = 0; ks < 2; ++ks)
            #pragma unroll
            for (int i = 0; i < 4; ++i)
                #pragma unroll
                for (int n = 0; n < 2; ++n)
                    acc[i][n + 2] = __builtin_amdgcn_mfma_f32_16x16x32_bf16(
                        aF[i][ks], bF1[n][ks], acc[i][n + 2], 0, 0, 0);
        __builtin_amdgcn_s_setprio(0);
        __builtin_amdgcn_s_barrier();
        __builtin_amdgcn_sched_barrier(0);

        // ---------------- PHASE 2 : (mh1, nh1)
        #pragma unroll
        for (int i = 0; i < 4; ++i)
            #pragma unroll
            for (int ks = 0; ks < 2; ++ks)
                aF[i][ks] = LDSREAD(cb0 + ((abase + ((i + 4) << 11) + (ks << 10)) ^ xlane));
        if (kt + 2 < NKT) STAGE(pB, 32768, cur, 0, kt + 2);
        __builtin_amdgcn_s_barrier();
        __builtin_amdgcn_sched_barrier(0);
        __builtin_amdgcn_s_setprio(1);
        #pragma unroll
        for (int ks = 0; ks < 2; ++ks)
            #pragma unroll
            for (int i = 0; i < 4; ++i)
                #pragma unroll
                for (int n = 0; n < 2; ++n)
                    acc[i + 4][n + 2] = __builtin_amdgcn_mfma_f32_16x16x32_bf16(
                        aF[i][ks], bF1[n][ks], acc[i + 4][n + 2], 0, 0, 0);
        __builtin_amdgcn_s_setprio(0);
        __builtin_amdgcn_s_barrier();
        __builtin_amdgcn_sched_barrier(0);

        // ---------------- PHASE 3 : (mh1, nh0)  (aF=mh1, bF0 held from P0)
        if (kt + 2 < NKT) {
            STAGE(pB, 32768, cur, 1, kt + 2);
            asm volatile("s_waitcnt vmcnt(4)" ::: "memory");  // tile kt+1 landed; kt+2 B in flight
        } else {
            asm volatile("s_waitcnt vmcnt(0)" ::: "memory");
        }
        __builtin_amdgcn_s_barrier();
        __builtin_amdgcn_sched_barrier(0);
        __builtin_amdgcn_s_setprio(1);
        #pragma unroll
        for (int ks = 0; ks < 2; ++ks)
            #pragma unroll
            for (int i = 0; i < 4; ++i)
                #pragma unroll
                for (int n = 0; n < 2; ++n)
                    acc[i + 4][n] = __builtin_amdgcn_mfma_f32_16x16x32_bf16(
                        aF[i][ks], bF0[n][ks], acc[i + 4][n], 0, 0, 0);
        __builtin_amdgcn_s_setprio(0);
        __builtin_amdgcn_s_barrier();
        __builtin_amdgcn_sched_barrier(0);
    }

    // epilogue: C write.  D frag: row=(lane>>4)*4+j (m), col=lane&15 (n)
    const int crow0 = bm * 256 + wr * 128 + ((lane >> 4) << 2);
    const int ccol0 = bn * 256 + wc * 64 + (lane & 15);
    #pragma unroll
    for (int fm = 0; fm < 8; ++fm)
        #pragma unroll
        for (int fn = 0; fn < 4; ++fn) {
            int row = crow0 + fm * 16;
            int col = ccol0 + fn * 16;
            #pragma unroll
            for (int j = 0; j < 4; ++j)
                C[(size_t)(row + j) * VV + col] = acc[fm][fn][j];
        }
}

// ---------------------------------------------------------------------------
extern "C" void kernel_launch(void* const* d_in, const int* in_sizes, int n_in,
                              void* d_out, int out_size, void* d_ws, size_t ws_size,
                              hipStream_t stream) {
    const float* h_in      = (const float*)d_in[0];
    const float* router_w  = (const float*)d_in[1];
    const float* router_b  = (const float*)d_in[2];
    const float* expert_B  = (const float*)d_in[3];
    const float* expert_A  = (const float*)d_in[4];
    const float* deep_B    = (const float*)d_in[5];
    const float* deep_A    = (const float*)d_in[6];
    const float* lm_head_w = (const float*)d_in[7];

    float* out = (float*)d_out;
    float* router_logits_out = out + (size_t)NTOK * VV;

    unsigned short* h_bf = (unsigned short*)d_ws;
    unsigned short* w_bf = (unsigned short*)((char*)d_ws + (size_t)NTOK * HD * 2);

    fused_layers<<<dim3(NTOK / 4), dim3(256), 0, stream>>>(
        h_in, router_w, router_b, expert_B, expert_A, deep_B, deep_A,
        router_logits_out, h_bf);

    cvt_kernel<<<dim3(4096), dim3(256), 0, stream>>>(
        (const float4*)lm_head_w, (ushort4*)w_bf, VV * HD / 4);

    lm_gemm256<<<dim3((NTOK / 256) * (VV / 256)), dim3(512), 0, stream>>>(
        h_bf, w_bf, out);
}